// Round 6
// baseline (188.927 us; speedup 1.0000x reference)
//
#include <hip/hip_runtime.h>

// Post_Prob_GS: B=8, N=256 points, grid 128x128 (HW=16384), stride 4.
// out[b, n, hw] = softmax over n of likelihood; n==256 is the background term.
//
// Round 6 structure:
//  - prep_kernel: packs per-point coeffs (expanded quadratic, log2e-scaled).
//  - reduce_kernel: per (b,hw) computes m2 = mf + log2(sum) into ws; writes
//    the background output row. (scalar coeff loads, LDS group-merge)
//  - store_kernel: ONE block per (b,n) row (2048 blocks, not 32k: round-5's
//    32k tiny blocks were workgroup-dispatch-bound). Each block streams its
//    full 64KB row in 16 iterations of 1KB-per-wave float4 stores; coeffs
//    loaded once per block via scalar path.

#define HWC 16384
#define NPTS 256
#define NBATCH 8

#define K_LOG2E 1.4426950408889634f
// log2e*(-0.5*100^2) + log2(0.15)
#define BK_CONST (-7216.2121700389835f)

__global__ __launch_bounds__(256) void prep_kernel(
    const float* __restrict__ scale,     // (B,N,2)
    const float* __restrict__ rotation,  // (B,N,1)
    const float* __restrict__ points,    // (B,N,2)
    float4* __restrict__ P)              // (B*N) x 2 float4
{
    const int i = blockIdx.x * 256 + threadIdx.x;   // 0..2047 = b*256+n
    if (i >= NBATCH * NPTS) return;

    float sx = fminf(fmaxf(32.0f * scale[i * 2 + 0], 2.0f), 100.0f);
    float sy = fminf(fmaxf(32.0f * scale[i * 2 + 1], 2.0f), 100.0f);
    float sx2 = sx * sx, sy2 = sy * sy;

    float th = rotation[i];
    float s, c;
    sincosf(th, &s, &c);
    float cov_a = c * c * sx2 + s * s * sy2;
    float cov_b = c * s * (sx2 - sy2);
    float cov_d = s * s * sx2 + c * c * sy2;
    float det  = sx2 * sy2;
    float rdet = 1.0f / det;

    // z = -0.5*(inv_a dx^2 + 2 inv_b dx dy + inv_d dy^2); all scaled by log2e
    float KA = -0.5f * K_LOG2E * (cov_d * rdet);
    float KB =         K_LOG2E * (cov_b * rdet);
    float KD = -0.5f * K_LOG2E * (cov_a * rdet);

    float px = points[i * 2 + 0];
    float py = points[i * 2 + 1];

    // expand: zK = KA*gx^2 + KB*gx*gy + KD*gy^2 + cx*gx + cy*gy + cz
    float cx = -(2.0f * KA * px + KB * py);
    float cy = -(KB * px + 2.0f * KD * py);
    float cz = KA * px * px + KB * px * py + KD * py * py;

    float l2det = log2f(det);
    float HLK = -0.5f * l2det;

    P[i * 2 + 0] = make_float4(KA, KB, KD, cx);
    P[i * 2 + 1] = make_float4(cy, cz + HLK, HLK, l2det);
}

#define LIKE(q0, q1) fmaf((q0).x, gxx, fmaf((q0).y, gxy, fmaf((q0).z, gyy, \
                     fmaf((q0).w, gx,  fmaf((q1).x, gy, (q1).y)))))

// m2[b,hw] = softmax log-normalizer (log2 domain); also writes bk output row.
__global__ __launch_bounds__(512) void reduce_kernel(
    const float4* __restrict__ P,    // packed coeffs in ws
    float* __restrict__ m2arr,       // (B, HW) in ws
    float* __restrict__ out)         // (B, 257, HW) -- bk row only
{
    __shared__ float sM[512];
    __shared__ float sBZ[512];
    __shared__ float sBLD[512];
    __shared__ float sS[512];

    const int b      = blockIdx.x >> 8;          // 256 blocks per batch
    const int hwbase = (blockIdx.x & 255) << 6;  // 64 hw per block
    const int tid    = threadIdx.x;
    const int h      = tid & 63;                 // hw within block (lane)
    const int hw     = hwbase + h;
    // n-group 0..7; readfirstlane => SGPR => scalar coefficient loads
    const int g      = __builtin_amdgcn_readfirstlane(tid >> 6);

    const float gx = (float)((hw & 127) * 4 + 2);
    const float gy = (float)((hw >> 7) * 4 + 2);
    const float gxx = gx * gx, gxy = gx * gy, gyy = gy * gy;

    const float4* __restrict__ Pb = P + (b * NPTS + g * 32) * 2;

    // ---- pass A: per-thread max + first-argmax over 32 points (streamed) ----
    float m = -INFINITY, bz = -INFINITY, bld = 0.0f;
    #pragma unroll 8
    for (int i = 0; i < 32; ++i) {
        float4 q0 = Pb[i * 2 + 0];
        float4 q1 = Pb[i * 2 + 1];
        float like = LIKE(q0, q1);
        m = fmaxf(m, like);
        float z = like - q1.z;
        bool gt = z > bz;               // strict > : first occurrence wins
        bz  = gt ? z    : bz;
        bld = gt ? q1.w : bld;
    }
    sM[tid] = m; sBZ[tid] = bz; sBLD[tid] = bld;
    __syncthreads();

    // merge groups in ascending g (== ascending n: first-max wins)
    float mf = sM[h], bzf = sBZ[h], bldf = sBLD[h];
    #pragma unroll
    for (int q = 1; q < 8; ++q) {
        mf = fmaxf(mf, sM[h + q * 64]);
        float zq = sBZ[h + q * 64];
        bool gt = zq > bzf;
        bzf  = gt ? zq : bzf;
        bldf = gt ? sBLD[h + q * 64] : bldf;
    }
    const float bk = BK_CONST - bzf - bldf;
    mf = fmaxf(mf, bk);

    // ---- pass B: sum of exp2 (recompute likes; cheap on scalar-load path) ----
    float s = 0.0f;
    #pragma unroll 8
    for (int i = 0; i < 32; ++i) {
        float4 q0 = Pb[i * 2 + 0];
        float4 q1 = Pb[i * 2 + 1];
        s += exp2f(LIKE(q0, q1) - mf);
    }
    sS[tid] = s;
    __syncthreads();

    float sum = exp2f(bk - mf);
    #pragma unroll
    for (int q = 0; q < 8; ++q) sum += sS[h + q * 64];
    const float m2 = mf + log2f(sum);   // folds 1/sum into the exponent

    if (tid < 64) {
        m2arr[b * HWC + hw] = m2;
        out[((size_t)b * 257 + 256) * HWC + hw] = exp2f(bk - m2);
    }
}

// One (b,n) row per block; block streams its whole 64KB row in 16 iterations.
__global__ __launch_bounds__(256) void store_kernel(
    const float4* __restrict__ P,    // packed coeffs in ws
    const float* __restrict__ m2arr, // (B, HW) in ws
    float* __restrict__ out)         // (B, 257, HW)
{
    const int bn  = blockIdx.x;          // 0..2047 = b*256+n (wave-uniform)
    const int b   = bn >> 8;
    const int tid = threadIdx.x;

    // coeffs: uniform address -> scalar loads, once per block
    const float4 q0 = P[bn * 2 + 0];
    const float4 q1 = P[bn * 2 + 1];

    float* __restrict__ dst = out + (size_t)(bn + b) * HWC;   // row b*257+n
    const float* __restrict__ m2b = m2arr + b * HWC;

    #pragma unroll 4
    for (int it = 0; it < 16; ++it) {
        const int hw = it * 1024 + tid * 4;       // 4-aligned, same y for 4 x
        const int x0 = hw & 127;
        const float gy = (float)((hw >> 7) * 4 + 2);
        const float gcoef = fmaf(q0.y, gy, q0.w);                   // KB*gy + cx
        const float base  = fmaf(fmaf(q0.z, gy, q1.x), gy, q1.y);   // KD*gy^2 + cy*gy + (cz+HLK)

        const float4 mm = *reinterpret_cast<const float4*>(m2b + hw);

        float gx0 = (float)(x0 * 4 + 2);
        float gx1 = gx0 + 4.0f, gx2 = gx0 + 8.0f, gx3 = gx0 + 12.0f;
        float4 e;
        e.x = exp2f(fmaf(fmaf(q0.x, gx0, gcoef), gx0, base) - mm.x);
        e.y = exp2f(fmaf(fmaf(q0.x, gx1, gcoef), gx1, base) - mm.y);
        e.z = exp2f(fmaf(fmaf(q0.x, gx2, gcoef), gx2, base) - mm.z);
        e.w = exp2f(fmaf(fmaf(q0.x, gx3, gcoef), gx3, base) - mm.w);

        *reinterpret_cast<float4*>(dst + hw) = e;
    }
}

extern "C" void kernel_launch(void* const* d_in, const int* in_sizes, int n_in,
                              void* d_out, int out_size, void* d_ws, size_t ws_size,
                              hipStream_t stream) {
    const float* scale    = (const float*)d_in[0];
    const float* rotation = (const float*)d_in[1];
    const float* points   = (const float*)d_in[2];
    float* out = (float*)d_out;
    float4* P  = (float4*)d_ws;                               // 64 KB
    float* m2  = (float*)((char*)d_ws + 65536);               // 512 KB
    (void)in_sizes; (void)n_in; (void)out_size; (void)ws_size;

    prep_kernel<<<dim3(NBATCH), dim3(256), 0, stream>>>(scale, rotation, points, P);
    reduce_kernel<<<dim3(NBATCH * (HWC / 64)), dim3(512), 0, stream>>>(P, m2, out);
    store_kernel<<<dim3(NBATCH * NPTS), dim3(256), 0, stream>>>(P, m2, out);
}

// Round 7
// 173.561 us; speedup vs baseline: 1.0885x; 1.0885x over previous
//
#include <hip/hip_runtime.h>

// Post_Prob_GS: B=8, N=256 points, grid 128x128 (HW=16384), stride 4.
// out[b, n, hw] = softmax over n of likelihood; n==256 is the background term.
//
// Round 7 structure (fused, streaming stores):
//  - prep_kernel: packs per-point coeffs (expanded quadratic, log2e-scaled).
//  - fused_kernel: block = 512 threads = 8 waves; block owns 256 consecutive
//    hw cells; wave g owns n-group [32g,32g+32); lane l owns 4 consecutive
//    cells (one float4). All 8 waves cover the same 256 cells; per-cell
//    max/argmax/sum merged across waves via LDS (ascending g == ascending n
//    -> jnp.argmax first-max semantics). Pass C stores are 64 lanes x 16B =
//    1KB contiguous per wave-store (R3 counters showed the 256B n-walking
//    pattern runs at ~1.1-2 TB/s; this is the fill-kernel pattern at ~6).

#define HWC 16384
#define NPTS 256
#define NBATCH 8

#define K_LOG2E 1.4426950408889634f
// log2e*(-0.5*100^2) + log2(0.15)
#define BK_CONST (-7216.2121700389835f)

__global__ __launch_bounds__(256) void prep_kernel(
    const float* __restrict__ scale,     // (B,N,2)
    const float* __restrict__ rotation,  // (B,N,1)
    const float* __restrict__ points,    // (B,N,2)
    float4* __restrict__ P)              // (B*N) x 2 float4
{
    const int i = blockIdx.x * 256 + threadIdx.x;   // 0..2047 = b*256+n
    if (i >= NBATCH * NPTS) return;

    float sx = fminf(fmaxf(32.0f * scale[i * 2 + 0], 2.0f), 100.0f);
    float sy = fminf(fmaxf(32.0f * scale[i * 2 + 1], 2.0f), 100.0f);
    float sx2 = sx * sx, sy2 = sy * sy;

    float th = rotation[i];
    float s, c;
    sincosf(th, &s, &c);
    float cov_a = c * c * sx2 + s * s * sy2;
    float cov_b = c * s * (sx2 - sy2);
    float cov_d = s * s * sx2 + c * c * sy2;
    float det  = sx2 * sy2;
    float rdet = 1.0f / det;

    // z = -0.5*(inv_a dx^2 + 2 inv_b dx dy + inv_d dy^2); all scaled by log2e
    float KA = -0.5f * K_LOG2E * (cov_d * rdet);
    float KB =         K_LOG2E * (cov_b * rdet);
    float KD = -0.5f * K_LOG2E * (cov_a * rdet);

    float px = points[i * 2 + 0];
    float py = points[i * 2 + 1];

    // expand: zK = KA*gx^2 + KB*gx*gy + KD*gy^2 + cx*gx + cy*gy + cz
    float cx = -(2.0f * KA * px + KB * py);
    float cy = -(KB * px + 2.0f * KD * py);
    float cz = KA * px * px + KB * px * py + KD * py * py;

    float l2det = log2f(det);
    float HLK = -0.5f * l2det;

    P[i * 2 + 0] = make_float4(KA, KB, KD, cx);
    P[i * 2 + 1] = make_float4(cy, cz + HLK, HLK, l2det);
}

__global__ __launch_bounds__(512) void fused_kernel(
    const float4* __restrict__ P,   // packed coeffs in ws
    float* __restrict__ out)        // (B, 257, HW)
{
    __shared__ float4 sM[8][64];
    __shared__ float4 sBZ[8][64];
    __shared__ float4 sBLD[8][64];
    __shared__ float4 sS[8][64];

    const int b     = blockIdx.x >> 6;          // 64 chunks per batch
    const int chunk = blockIdx.x & 63;          // 256 consecutive hw per block
    const int tid   = threadIdx.x;
    const int l     = tid & 63;                 // lane
    const int g     = __builtin_amdgcn_readfirstlane(tid >> 6);  // n-group

    const int hw0 = chunk * 256 + l * 4;        // lane's 4 cells (same row)
    const float gy  = (float)((hw0 >> 7) * 4 + 2);
    const float gx0 = (float)((hw0 & 127) * 4 + 2);

    const float4* __restrict__ Pg = P + (b * NPTS + g * 32) * 2;

    // ---- pass A: per-wave (32 n) max + first-argmax for lane's 4 cells ----
    float m[4], bz[4], bld[4];
    #pragma unroll
    for (int j = 0; j < 4; ++j) { m[j] = -INFINITY; bz[j] = -INFINITY; bld[j] = 0.0f; }

    #pragma unroll 4
    for (int i = 0; i < 32; ++i) {
        float4 q0 = Pg[i * 2 + 0];
        float4 q1 = Pg[i * 2 + 1];
        float gcoef = fmaf(q0.y, gy, q0.w);                  // KB*gy + cx
        float base  = fmaf(fmaf(q0.z, gy, q1.x), gy, q1.y);  // KD*gy^2+cy*gy+cz+HLK
        #pragma unroll
        for (int j = 0; j < 4; ++j) {
            float gx = gx0 + 4.0f * j;
            float like = fmaf(fmaf(q0.x, gx, gcoef), gx, base);
            m[j] = fmaxf(m[j], like);
            float z = like - q1.z;
            bool gt = z > bz[j];        // strict > : first occurrence wins
            bz[j]  = gt ? z    : bz[j];
            bld[j] = gt ? q1.w : bld[j];
        }
    }
    sM[g][l]   = make_float4(m[0], m[1], m[2], m[3]);
    sBZ[g][l]  = make_float4(bz[0], bz[1], bz[2], bz[3]);
    sBLD[g][l] = make_float4(bld[0], bld[1], bld[2], bld[3]);
    __syncthreads();

    // merge across groups, ascending g (== ascending n: first-max wins)
    float mf[4], bzf[4], bldf[4];
    {
        float4 m0 = sM[0][l], z0 = sBZ[0][l], d0 = sBLD[0][l];
        mf[0]=m0.x; mf[1]=m0.y; mf[2]=m0.z; mf[3]=m0.w;
        bzf[0]=z0.x; bzf[1]=z0.y; bzf[2]=z0.z; bzf[3]=z0.w;
        bldf[0]=d0.x; bldf[1]=d0.y; bldf[2]=d0.z; bldf[3]=d0.w;
        #pragma unroll
        for (int q = 1; q < 8; ++q) {
            float4 mq = sM[q][l], zq = sBZ[q][l], dq = sBLD[q][l];
            const float mqa[4] = {mq.x, mq.y, mq.z, mq.w};
            const float zqa[4] = {zq.x, zq.y, zq.z, zq.w};
            const float dqa[4] = {dq.x, dq.y, dq.z, dq.w};
            #pragma unroll
            for (int j = 0; j < 4; ++j) {
                mf[j] = fmaxf(mf[j], mqa[j]);
                bool gt = zqa[j] > bzf[j];
                bzf[j]  = gt ? zqa[j] : bzf[j];
                bldf[j] = gt ? dqa[j] : bldf[j];
            }
        }
    }
    float bk[4];
    #pragma unroll
    for (int j = 0; j < 4; ++j) {
        bk[j] = BK_CONST - bzf[j] - bldf[j];
        mf[j] = fmaxf(mf[j], bk[j]);
    }

    // ---- pass B: per-wave partial sums of exp2, merge across groups ----
    float s[4] = {0.0f, 0.0f, 0.0f, 0.0f};
    #pragma unroll 4
    for (int i = 0; i < 32; ++i) {
        float4 q0 = Pg[i * 2 + 0];
        float4 q1 = Pg[i * 2 + 1];
        float gcoef = fmaf(q0.y, gy, q0.w);
        float base  = fmaf(fmaf(q0.z, gy, q1.x), gy, q1.y);
        #pragma unroll
        for (int j = 0; j < 4; ++j) {
            float gx = gx0 + 4.0f * j;
            float like = fmaf(fmaf(q0.x, gx, gcoef), gx, base);
            s[j] += exp2f(like - mf[j]);
        }
    }
    sS[g][l] = make_float4(s[0], s[1], s[2], s[3]);
    __syncthreads();

    float sum[4];
    #pragma unroll
    for (int j = 0; j < 4; ++j) sum[j] = exp2f(bk[j] - mf[j]);
    #pragma unroll
    for (int q = 0; q < 8; ++q) {
        float4 sq = sS[q][l];
        sum[0] += sq.x; sum[1] += sq.y; sum[2] += sq.z; sum[3] += sq.w;
    }
    float m2[4];
    #pragma unroll
    for (int j = 0; j < 4; ++j) m2[j] = mf[j] + log2f(sum[j]);

    // ---- pass C: streaming stores, 1KB contiguous per wave-store ----
    float* __restrict__ dst = out + ((size_t)b * 257 + g * 32) * HWC + hw0;
    #pragma unroll 4
    for (int i = 0; i < 32; ++i) {
        float4 q0 = Pg[i * 2 + 0];
        float4 q1 = Pg[i * 2 + 1];
        float gcoef = fmaf(q0.y, gy, q0.w);
        float base  = fmaf(fmaf(q0.z, gy, q1.x), gy, q1.y);
        float4 e;
        float gx;
        gx = gx0;         e.x = exp2f(fmaf(fmaf(q0.x, gx, gcoef), gx, base) - m2[0]);
        gx = gx0 + 4.0f;  e.y = exp2f(fmaf(fmaf(q0.x, gx, gcoef), gx, base) - m2[1]);
        gx = gx0 + 8.0f;  e.z = exp2f(fmaf(fmaf(q0.x, gx, gcoef), gx, base) - m2[2]);
        gx = gx0 + 12.0f; e.w = exp2f(fmaf(fmaf(q0.x, gx, gcoef), gx, base) - m2[3]);
        *reinterpret_cast<float4*>(dst + (size_t)i * HWC) = e;
    }
    if (g == 0) {   // background row, same 1KB-per-wave pattern
        float4 e;
        e.x = exp2f(bk[0] - m2[0]);
        e.y = exp2f(bk[1] - m2[1]);
        e.z = exp2f(bk[2] - m2[2]);
        e.w = exp2f(bk[3] - m2[3]);
        *reinterpret_cast<float4*>(out + ((size_t)b * 257 + 256) * HWC + hw0) = e;
    }
}

extern "C" void kernel_launch(void* const* d_in, const int* in_sizes, int n_in,
                              void* d_out, int out_size, void* d_ws, size_t ws_size,
                              hipStream_t stream) {
    const float* scale    = (const float*)d_in[0];
    const float* rotation = (const float*)d_in[1];
    const float* points   = (const float*)d_in[2];
    float* out = (float*)d_out;
    float4* P  = (float4*)d_ws;                               // 64 KB
    (void)in_sizes; (void)n_in; (void)out_size; (void)ws_size;

    prep_kernel<<<dim3(NBATCH), dim3(256), 0, stream>>>(scale, rotation, points, P);
    fused_kernel<<<dim3(NBATCH * 64), dim3(512), 0, stream>>>(P, out);
}

// Round 8
// 152.110 us; speedup vs baseline: 1.2420x; 1.1410x over previous
//
#include <hip/hip_runtime.h>

// Post_Prob_GS: B=8, N=256 points, grid 128x128 (HW=16384), stride 4.
// out[b, n, hw] = softmax over n of likelihood; n==256 is the background term.
//
// Round 8 = Round 4 (best so far, bench 146.3) with ONE change:
// all output stores are nontemporal (nt) -> stream past L2 instead of
// allocating dirty lines that evict in random order. Clean A/B to decide
// whether the ~2 TB/s effective store ceiling is the L2 write path (H1)
// or whether the eval loops are the real limiter (H2).

#define HWC 16384
#define NPTS 256
#define NBATCH 8

#define K_LOG2E 1.4426950408889634f
// log2e*(-0.5*100^2) + log2(0.15)
#define BK_CONST (-7216.2121700389835f)

__global__ __launch_bounds__(256) void prep_kernel(
    const float* __restrict__ scale,     // (B,N,2)
    const float* __restrict__ rotation,  // (B,N,1)
    const float* __restrict__ points,    // (B,N,2)
    float4* __restrict__ P)              // (B*N) x 2 float4
{
    const int i = blockIdx.x * 256 + threadIdx.x;   // 0..2047 = b*256+n
    if (i >= NBATCH * NPTS) return;

    float sx = fminf(fmaxf(32.0f * scale[i * 2 + 0], 2.0f), 100.0f);
    float sy = fminf(fmaxf(32.0f * scale[i * 2 + 1], 2.0f), 100.0f);
    float sx2 = sx * sx, sy2 = sy * sy;

    float th = rotation[i];
    float s, c;
    sincosf(th, &s, &c);
    float cov_a = c * c * sx2 + s * s * sy2;
    float cov_b = c * s * (sx2 - sy2);
    float cov_d = s * s * sx2 + c * c * sy2;
    float det  = sx2 * sy2;
    float rdet = 1.0f / det;

    // z = -0.5*(inv_a dx^2 + 2 inv_b dx dy + inv_d dy^2); all scaled by log2e
    float KA = -0.5f * K_LOG2E * (cov_d * rdet);
    float KB =         K_LOG2E * (cov_b * rdet);
    float KD = -0.5f * K_LOG2E * (cov_a * rdet);

    float px = points[i * 2 + 0];
    float py = points[i * 2 + 1];

    // expand: zK = KA*gx^2 + KB*gx*gy + KD*gy^2 + cx*gx + cy*gy + cz
    float cx = -(2.0f * KA * px + KB * py);
    float cy = -(KB * px + 2.0f * KD * py);
    float cz = KA * px * px + KB * px * py + KD * py * py;

    float l2det = log2f(det);
    float HLK = -0.5f * l2det;

    P[i * 2 + 0] = make_float4(KA, KB, KD, cx);
    P[i * 2 + 1] = make_float4(cy, cz + HLK, HLK, l2det);
}

#define LIKE(q0, q1) fmaf((q0).x, gxx, fmaf((q0).y, gxy, fmaf((q0).z, gyy, \
                     fmaf((q0).w, gx,  fmaf((q1).x, gy, (q1).y)))))

__global__ __launch_bounds__(512) void post_prob_kernel(
    const float4* __restrict__ P,   // packed coeffs in ws
    float* __restrict__ out)        // (B, 257, HW)
{
    __shared__ float sM[512];
    __shared__ float sBZ[512];
    __shared__ float sBLD[512];
    __shared__ float sS[512];

    const int b      = blockIdx.x >> 8;          // 256 blocks per batch
    const int hwbase = (blockIdx.x & 255) << 6;  // 64 hw per block
    const int tid    = threadIdx.x;
    const int h      = tid & 63;                 // hw within block (lane)
    const int hw     = hwbase + h;
    // n-group 0..7; readfirstlane => SGPR => scalar coefficient loads
    const int g      = __builtin_amdgcn_readfirstlane(tid >> 6);

    const float gx = (float)((hw & 127) * 4 + 2);
    const float gy = (float)((hw >> 7) * 4 + 2);
    const float gxx = gx * gx, gxy = gx * gy, gyy = gy * gy;

    const float4* __restrict__ Pb = P + (b * NPTS + g * 32) * 2;

    // ---- pass A: compute 32 likes into register cache; track max + argmax ----
    float lk[32];
    float m = -INFINITY, bz = -INFINITY, bld = 0.0f;
    #pragma unroll
    for (int i = 0; i < 32; ++i) {
        float4 q0 = Pb[i * 2 + 0];
        float4 q1 = Pb[i * 2 + 1];
        float like = LIKE(q0, q1);
        lk[i] = like;
        m = fmaxf(m, like);
        float z = like - q1.z;
        bool gt = z > bz;               // strict > : first occurrence wins
        bz  = gt ? z    : bz;
        bld = gt ? q1.w : bld;
    }
    sM[tid] = m; sBZ[tid] = bz; sBLD[tid] = bld;
    __syncthreads();

    // merge groups in ascending g (== ascending n: first-max wins)
    float mf = sM[h], bzf = sBZ[h], bldf = sBLD[h];
    #pragma unroll
    for (int q = 1; q < 8; ++q) {
        mf = fmaxf(mf, sM[h + q * 64]);
        float zq = sBZ[h + q * 64];
        bool gt = zq > bzf;
        bzf  = gt ? zq : bzf;
        bldf = gt ? sBLD[h + q * 64] : bldf;
    }
    const float bk = BK_CONST - bzf - bldf;
    mf = fmaxf(mf, bk);

    // ---- pass B: exponentiate cache in place, accumulate partial sum ----
    float s = 0.0f;
    #pragma unroll
    for (int i = 0; i < 32; ++i) {
        float e = exp2f(lk[i] - mf);
        lk[i] = e;
        s += e;
    }
    sS[tid] = s;
    __syncthreads();

    float sum = exp2f(bk - mf);
    #pragma unroll
    for (int q = 0; q < 8; ++q) sum += sS[h + q * 64];
    const float inv = 1.0f / sum;

    // ---- pass C: normalized nontemporal writes (64x4B contiguous per wave) ----
    float* __restrict__ outb = out + ((size_t)b * 257 + g * 32) * HWC + hw;
    #pragma unroll
    for (int i = 0; i < 32; ++i)
        __builtin_nontemporal_store(lk[i] * inv, &outb[(size_t)i * HWC]);

    if (tid < 64)
        __builtin_nontemporal_store(exp2f(bk - mf) * inv,
                                    &out[((size_t)b * 257 + 256) * HWC + hw]);
}

extern "C" void kernel_launch(void* const* d_in, const int* in_sizes, int n_in,
                              void* d_out, int out_size, void* d_ws, size_t ws_size,
                              hipStream_t stream) {
    const float* scale    = (const float*)d_in[0];
    const float* rotation = (const float*)d_in[1];
    const float* points   = (const float*)d_in[2];
    float* out = (float*)d_out;
    float4* P  = (float4*)d_ws;
    (void)in_sizes; (void)n_in; (void)out_size; (void)ws_size;

    prep_kernel<<<dim3(NBATCH), dim3(256), 0, stream>>>(scale, rotation, points, P);
    post_prob_kernel<<<dim3(NBATCH * (HWC / 64)), dim3(512), 0, stream>>>(P, out);
}